// Round 15
// baseline (106.867 us; speedup 1.0000x reference)
//
#include <hip/hip_runtime.h>

// 3D trilinear warp (grid_sample, align_corners=True, border padding).
// image: (B=2, 1, 160, 192, 192) f32 | ddf: (B,3,D,H,W) f32 (dz,dy,dx voxels)
//
// Round-15: R11 structure with a bf16 LDS tile stored/read UNIFORMLY as u32.
//  - R14's failure suspect: mixed-type LDS access (ushort[] written via
//    uint2*) = TBAA violation + an off-by-one u32 OOB on even pair reads.
//    Here ALL tile accesses are `unsigned` (u32): writes store two packed
//    bf16 (round-to-nearest via +0x8000), reads fetch u32 and extract
//    halves with branchless selects. +pad words for the pair-read overrun.
//  - Window 32 slices x 52x23 drops 153 -> 76.6 KB; block total ~80.7 KB ->
//    TWO blocks/CU (32 waves): block A's compute overlaps block B's
//    staging/barriers (the measured 1-block/CU phase-serialization stall).
//    __launch_bounds__(1024,8) caps VGPR at 64 to allow both blocks.
//  - Everything else identical to R11 (85.3us): 2304 blocks (9/CU), split-
//    phase staging (T14), payload miss queue + exact-f32 global epilogue,
//    XCD-chunked swizzle.

typedef float f32x4 __attribute__((ext_vector_type(4)));
typedef float f32x2 __attribute__((ext_vector_type(2)));

constexpr int D_ = 160, H_ = 192, W_ = 192;
constexpr int HW_ = H_ * W_;
constexpr int N_  = D_ * HW_;

constexpr int TX_ = 32, TY_ = 8;
constexpr int XT_ = W_ / TX_;               // 6
constexpr int YT_ = H_ / TY_;               // 24
constexpr int ZH_ = 8;
constexpr int ZRUN_ = D_ / ZH_;             // 20
constexpr int NBLK_ = XT_ * YT_ * ZH_ * 2;  // 2304 = 9 * 256 exactly

constexpr int RX_ = 52, RY_ = 23, NZ_ = 32;
constexpr int SLICE_ = RX_ * RY_;           // 1196 elements (even)
constexpr int CPS_ = SLICE_ / 4;            // 299 4-elem chunks per slice
constexpr int CPR_ = RX_ / 4;               // 13 chunks per row
constexpr int LIM_ = NZ_ * SLICE_ - RX_ - 2;// 38218: max safe base offset
constexpr int TILE32_ = NZ_ * SLICE_ / 2 + 4; // 19140 u32 (+pad for pair read)
constexpr int QCAP_ = 256;

__device__ __forceinline__ unsigned bfpack(float lo, float hi) {
    unsigned a = (__builtin_bit_cast(unsigned, lo) + 0x8000u) >> 16;
    unsigned b = (__builtin_bit_cast(unsigned, hi) + 0x8000u) & 0xFFFF0000u;
    return a | b;
}

__global__ __launch_bounds__(1024, 8) void warp3d_kernel(
    const float* __restrict__ img,
    const float* __restrict__ ddf,
    float* __restrict__ out)
{
    __shared__ unsigned tile32[TILE32_];    // 76,560 B
    __shared__ f32x4 qdat[QCAP_];           // 4,096 B
    __shared__ int   qcount;

    constexpr int CPX = NBLK_ / 8;          // 288
    int bid = blockIdx.x;
    int swz = (bid & 7) * CPX + (bid >> 3);

    int tx = swz % XT_;  int t1 = swz / XT_;
    int ty = t1 % YT_;   int t2 = t1 / YT_;
    int zh = t2 % ZH_;   int b  = t2 / ZH_;

    int zlo = zh * ZRUN_;
    int vz0 = zlo - 4;                      // virtual window origin (may be <0)
    int rx = min(max(tx * TX_ - 8, 0), W_ - RX_);
    int ry = min(max(ty * TY_ - 7, 0), H_ - RY_);

    const float* im = img + (size_t)b * N_;
    const float* dp = ddf + (size_t)b * 3 * N_;
    float*       op = out + (size_t)b * N_;

    int tid = threadIdx.x;
    int xi = tid & 31;
    int yy = (tid >> 5) & 7;
    int zz = tid >> 8;                      // 0..3

    int x = tx * TX_ + xi;
    int y = ty * TY_ + yy;
    int s0 = ((zlo + zz) * H_ + y) * W_ + x;

    // ---- ddf loads for all 5 voxels (latency hides under phase-A staging) --
    float ddz[5], ddy[5], ddxv[5];
#pragma unroll
    for (int k = 0; k < 5; ++k) {
        int s = s0 + k * 4 * HW_;
        ddz[k]  = __builtin_nontemporal_load(dp + s);
        ddy[k]  = __builtin_nontemporal_load(dp + N_ + s);
        ddxv[k] = __builtin_nontemporal_load(dp + 2 * N_ + s);
    }

    if (tid == 0) qcount = 0;

    // ---- phase A: stage slices [max(0,vz0), zlo+12) -> slots [.,16) ----
    int pzA0 = max(0, vz0);
    int pcntA = (zlo + 12 - pzA0) * CPS_;
    for (int c = tid; c < pcntA; c += 1024) {
        int si  = c / CPS_;
        int rem = c - si * CPS_;
        int zs  = pzA0 + si;
        int row = rem / CPR_;
        int col = rem - row * CPR_;
        f32x4 v = *(const f32x4*)(im + (zs * H_ + ry + row) * W_ + rx + col * 4);
        int p = (zs - vz0) * (SLICE_ / 2) + rem * 2;   // u32 index (even)
        tile32[p]     = bfpack(v.x, v.y);
        tile32[p + 1] = bfpack(v.z, v.w);
    }
    __syncthreads();

    // read elements (o, o+1) from the bf16 tile; o arbitrary parity
    auto ldpair = [&](int o, float& e0, float& e1) {
        int p = o >> 1;
        unsigned w0 = tile32[p];
        unsigned w1 = tile32[p + 1];
        bool odd = (o & 1) != 0;
        unsigned u0 = odd ? (w0 & 0xFFFF0000u) : (w0 << 16);
        unsigned u1 = odd ? (w1 << 16)         : (w0 & 0xFFFF0000u);
        e0 = __builtin_bit_cast(float, u0);
        e1 = __builtin_bit_cast(float, u1);
    };

    // global gather (overflow + epilogue path; exact f32)
    auto gglobal = [&](int vx, int vy, int vz,
                       float gdx, float gdy, float gdz) -> float {
        float ix = fminf(fmaxf((float)vx + gdx, 0.f), (float)(W_ - 1));
        float iy = fminf(fmaxf((float)vy + gdy, 0.f), (float)(H_ - 1));
        float iz = fminf(fmaxf((float)vz + gdz, 0.f), (float)(D_ - 1));
        int x0 = min((int)ix, W_ - 2);
        int y0 = min((int)iy, H_ - 2);
        int z0 = min((int)iz, D_ - 2);
        float wx = ix - (float)x0;
        float wy = iy - (float)y0;
        float wz = iz - (float)z0;
        const float* p = im + (z0 * HW_ + y0 * W_ + x0);
        f32x2 a = *(const f32x2*)(p);
        f32x2 c = *(const f32x2*)(p + W_);
        f32x2 e = *(const f32x2*)(p + HW_);
        f32x2 f = *(const f32x2*)(p + HW_ + W_);
        float c00 = a.x + (a.y - a.x) * wx;
        float c01 = c.x + (c.y - c.x) * wx;
        float c10 = e.x + (e.y - e.x) * wx;
        float c11 = f.x + (f.y - f.x) * wx;
        float c0 = c00 + (c01 - c00) * wy;
        float c1 = c10 + (c11 - c10) * wy;
        return c0 + (c1 - c0) * wz;
    };

    // one voxel: LDS window read (single final-offset clamp) + queue on miss
    auto process = [&](int z, int s, float gdx, float gdy, float gdz,
                       int uzTop) {
        float ix = fminf(fmaxf((float)x + gdx, 0.f), (float)(W_ - 1));
        float iy = fminf(fmaxf((float)y + gdy, 0.f), (float)(H_ - 1));
        float iz = fminf(fmaxf((float)z + gdz, 0.f), (float)(D_ - 1));

        int x0 = min((int)ix, W_ - 2);
        int y0 = min((int)iy, H_ - 2);
        int z0 = min((int)iz, D_ - 2);
        float wx = ix - (float)x0;
        float wy = iy - (float)y0;
        float wz = iz - (float)z0;

        int ux = x0 - rx, uy = y0 - ry, uz = z0 - vz0;
        bool in = ((unsigned)ux <= (unsigned)(RX_ - 2)) &
                  ((unsigned)uy <= (unsigned)(RY_ - 2)) &
                  ((unsigned)uz <= (unsigned)uzTop);

        int o0 = uz * SLICE_ + uy * RX_ + ux;   // raw; may be out of range
        o0 = min(max(o0, 0), LIM_);             // memory-safe (garbage on miss)
        int o1 = min(o0 + SLICE_, LIM_);

        float v000, v001, v010, v011, v100, v101, v110, v111;
        ldpair(o0,       v000, v001);
        ldpair(o0 + RX_, v010, v011);
        ldpair(o1,       v100, v101);
        ldpair(o1 + RX_, v110, v111);

        float c00 = v000 + (v001 - v000) * wx;
        float c01 = v010 + (v011 - v010) * wx;
        float c10 = v100 + (v101 - v100) * wx;
        float c11 = v110 + (v111 - v110) * wx;
        float c0 = c00 + (c01 - c00) * wy;
        float c1 = c10 + (c11 - c10) * wy;
        float res = c0 + (c1 - c0) * wz;

        bool do_store = in;
        if (!in) {
            int idx = atomicAdd(&qcount, 1);
            if (idx < QCAP_) {
                qdat[idx] = f32x4{__int_as_float(s), gdx, gdy, gdz};
            } else {
                res = gglobal(x, y, z, gdx, gdy, gdz);
                do_store = true;
            }
        }
        if (do_store) __builtin_nontemporal_store(res, op + s);
    };

    // ---- phase B issue: load slices [zlo+12, min(D,zlo+28)) into regs ----
    int zB0 = zlo + 12;
    int pcntB = (min(D_, zlo + 28) - zB0) * CPS_;
    f32x4 bv0, bv1, bv2, bv3, bv4;
    int   sl0, sl1, sl2, sl3, sl4;      // u32 index of chunk start (even)
    bool  bm0, bm1, bm2, bm3, bm4;
    {
#define ISSUE_B(J, BV, SL, BM)                                                 \
        {                                                                      \
            int c = tid + (J << 10);                                           \
            BM = c < pcntB;                                                    \
            int si  = c / CPS_;                                                \
            int rem = c - si * CPS_;                                           \
            int zs  = zB0 + si;                                                \
            SL = (zs - vz0) * (SLICE_ / 2) + rem * 2;                          \
            if (BM) {                                                          \
                int row = rem / CPR_;                                          \
                int col = rem - row * CPR_;                                    \
                BV = *(const f32x4*)(im + (zs * H_ + ry + row) * W_ + rx + col * 4); \
            }                                                                  \
        }
        ISSUE_B(0, bv0, sl0, bm0)
        ISSUE_B(1, bv1, sl1, bm1)
        ISSUE_B(2, bv2, sl2, bm2)
        ISSUE_B(3, bv3, sl3, bm3)
        ISSUE_B(4, bv4, sl4, bm4)
#undef ISSUE_B
    }

    // ---- compute k=0,1 against phase-A window (slots 0..15 -> uz<=14) ----
    process(zlo + zz,     s0,           ddxv[0], ddy[0], ddz[0], 14);
    process(zlo + zz + 4, s0 + 4 * HW_, ddxv[1], ddy[1], ddz[1], 14);

    // ---- commit phase-B regs to LDS slots 16..31 (disjoint from A reads) --
    if (bm0) { tile32[sl0] = bfpack(bv0.x, bv0.y); tile32[sl0 + 1] = bfpack(bv0.z, bv0.w); }
    if (bm1) { tile32[sl1] = bfpack(bv1.x, bv1.y); tile32[sl1 + 1] = bfpack(bv1.z, bv1.w); }
    if (bm2) { tile32[sl2] = bfpack(bv2.x, bv2.y); tile32[sl2 + 1] = bfpack(bv2.z, bv2.w); }
    if (bm3) { tile32[sl3] = bfpack(bv3.x, bv3.y); tile32[sl3 + 1] = bfpack(bv3.z, bv3.w); }
    if (bm4) { tile32[sl4] = bfpack(bv4.x, bv4.y); tile32[sl4 + 1] = bfpack(bv4.z, bv4.w); }
    __syncthreads();

    // ---- compute k=2..4 with the full window (uz<=30) ----
    process(zlo + zz + 8,  s0 + 8 * HW_,  ddxv[2], ddy[2], ddz[2], 30);
    process(zlo + zz + 12, s0 + 12 * HW_, ddxv[3], ddy[3], ddz[3], 30);
    process(zlo + zz + 16, s0 + 16 * HW_, ddxv[4], ddy[4], ddz[4], 30);

    __syncthreads();

    // ---- epilogue: resolve queued misses (ddf from queue, gathers L2-hot) --
    int n = min(qcount, QCAP_);
    for (int i = tid; i < n; i += 1024) {
        f32x4 q = qdat[i];
        int sq = __float_as_int(q.x);
        int zq = sq / HW_;
        int rq = sq - zq * HW_;
        int yq = rq / W_;
        int xq = rq - yq * W_;
        float res = gglobal(xq, yq, zq, q.y, q.z, q.w);
        op[sq] = res;
    }
}

extern "C" void kernel_launch(void* const* d_in, const int* in_sizes, int n_in,
                              void* d_out, int out_size, void* d_ws, size_t ws_size,
                              hipStream_t stream) {
    const float* img = (const float*)d_in[0];
    const float* ddf = (const float*)d_in[1];
    float*       out = (float*)d_out;

    warp3d_kernel<<<NBLK_, 1024, 0, stream>>>(img, ddf, out);
}

// Round 16
// 88.522 us; speedup vs baseline: 1.2072x; 1.2072x over previous
//
#include <hip/hip_runtime.h>

// 3D trilinear warp (grid_sample, align_corners=True, border padding).
// image: (B=2, 1, 160, 192, 192) f32 | ddf: (B,3,D,H,W) f32 (dz,dy,dx voxels)
//
// Round-16: R15 (bf16-in-LDS, 2 blocks/CU) WITHOUT the register cap.
//  - R15's regression was __launch_bounds__(1024,8): compiler allocated
//    VGPR=32 and spilled ~150MB to scratch (WRITE_SIZE 53->154MB). Plain
//    __launch_bounds__(1024) (as R11, 52 VGPR natural) lets the HW still
//    co-schedule 2 blocks/CU (52<=64-VGPR budget, LDS 80.9KBx2 fits 160KB)
//    with zero spills.
//  - Tile: u32-only access, two packed bf16/word (round-to-nearest).
//    Window 32 slices x 52x23 = 76.6 KB. Occupancy 76% measured in R15.
//  - Everything else = R11: 2304 blocks (9/CU), split-phase staging (T14),
//    payload miss queue + exact-f32 global epilogue, XCD-chunked swizzle.

typedef float f32x4 __attribute__((ext_vector_type(4)));
typedef float f32x2 __attribute__((ext_vector_type(2)));

constexpr int D_ = 160, H_ = 192, W_ = 192;
constexpr int HW_ = H_ * W_;
constexpr int N_  = D_ * HW_;

constexpr int TX_ = 32, TY_ = 8;
constexpr int XT_ = W_ / TX_;               // 6
constexpr int YT_ = H_ / TY_;               // 24
constexpr int ZH_ = 8;
constexpr int ZRUN_ = D_ / ZH_;             // 20
constexpr int NBLK_ = XT_ * YT_ * ZH_ * 2;  // 2304 = 9 * 256 exactly

constexpr int RX_ = 52, RY_ = 23, NZ_ = 32;
constexpr int SLICE_ = RX_ * RY_;           // 1196 elements (even)
constexpr int CPS_ = SLICE_ / 4;            // 299 4-elem chunks per slice
constexpr int CPR_ = RX_ / 4;               // 13 chunks per row
constexpr int LIM_ = NZ_ * SLICE_ - RX_ - 2;// 38218: max safe base offset
constexpr int TILE32_ = NZ_ * SLICE_ / 2 + 4; // 19140 u32 (+pad for pair read)
constexpr int QCAP_ = 256;

__device__ __forceinline__ unsigned bfpack(float lo, float hi) {
    unsigned a = (__builtin_bit_cast(unsigned, lo) + 0x8000u) >> 16;
    unsigned b = (__builtin_bit_cast(unsigned, hi) + 0x8000u) & 0xFFFF0000u;
    return a | b;
}

__global__ __launch_bounds__(1024) void warp3d_kernel(
    const float* __restrict__ img,
    const float* __restrict__ ddf,
    float* __restrict__ out)
{
    __shared__ unsigned tile32[TILE32_];    // 76,560 B
    __shared__ f32x4 qdat[QCAP_];           // 4,096 B
    __shared__ int   qcount;

    constexpr int CPX = NBLK_ / 8;          // 288
    int bid = blockIdx.x;
    int swz = (bid & 7) * CPX + (bid >> 3);

    int tx = swz % XT_;  int t1 = swz / XT_;
    int ty = t1 % YT_;   int t2 = t1 / YT_;
    int zh = t2 % ZH_;   int b  = t2 / ZH_;

    int zlo = zh * ZRUN_;
    int vz0 = zlo - 4;                      // virtual window origin (may be <0)
    int rx = min(max(tx * TX_ - 8, 0), W_ - RX_);
    int ry = min(max(ty * TY_ - 7, 0), H_ - RY_);

    const float* im = img + (size_t)b * N_;
    const float* dp = ddf + (size_t)b * 3 * N_;
    float*       op = out + (size_t)b * N_;

    int tid = threadIdx.x;
    int xi = tid & 31;
    int yy = (tid >> 5) & 7;
    int zz = tid >> 8;                      // 0..3

    int x = tx * TX_ + xi;
    int y = ty * TY_ + yy;
    int s0 = ((zlo + zz) * H_ + y) * W_ + x;

    // ---- ddf loads for all 5 voxels (latency hides under phase-A staging) --
    float ddz[5], ddy[5], ddxv[5];
#pragma unroll
    for (int k = 0; k < 5; ++k) {
        int s = s0 + k * 4 * HW_;
        ddz[k]  = __builtin_nontemporal_load(dp + s);
        ddy[k]  = __builtin_nontemporal_load(dp + N_ + s);
        ddxv[k] = __builtin_nontemporal_load(dp + 2 * N_ + s);
    }

    if (tid == 0) qcount = 0;

    // ---- phase A: stage slices [max(0,vz0), zlo+12) -> slots [.,16) ----
    int pzA0 = max(0, vz0);
    int pcntA = (zlo + 12 - pzA0) * CPS_;
    for (int c = tid; c < pcntA; c += 1024) {
        int si  = c / CPS_;
        int rem = c - si * CPS_;
        int zs  = pzA0 + si;
        int row = rem / CPR_;
        int col = rem - row * CPR_;
        f32x4 v = *(const f32x4*)(im + (zs * H_ + ry + row) * W_ + rx + col * 4);
        int p = (zs - vz0) * (SLICE_ / 2) + rem * 2;   // u32 index (even)
        tile32[p]     = bfpack(v.x, v.y);
        tile32[p + 1] = bfpack(v.z, v.w);
    }
    __syncthreads();

    // read elements (o, o+1) from the bf16 tile; o arbitrary parity
    auto ldpair = [&](int o, float& e0, float& e1) {
        int p = o >> 1;
        unsigned w0 = tile32[p];
        unsigned w1 = tile32[p + 1];
        bool odd = (o & 1) != 0;
        unsigned u0 = odd ? (w0 & 0xFFFF0000u) : (w0 << 16);
        unsigned u1 = odd ? (w1 << 16)         : (w0 & 0xFFFF0000u);
        e0 = __builtin_bit_cast(float, u0);
        e1 = __builtin_bit_cast(float, u1);
    };

    // global gather (overflow + epilogue path; exact f32)
    auto gglobal = [&](int vx, int vy, int vz,
                       float gdx, float gdy, float gdz) -> float {
        float ix = fminf(fmaxf((float)vx + gdx, 0.f), (float)(W_ - 1));
        float iy = fminf(fmaxf((float)vy + gdy, 0.f), (float)(H_ - 1));
        float iz = fminf(fmaxf((float)vz + gdz, 0.f), (float)(D_ - 1));
        int x0 = min((int)ix, W_ - 2);
        int y0 = min((int)iy, H_ - 2);
        int z0 = min((int)iz, D_ - 2);
        float wx = ix - (float)x0;
        float wy = iy - (float)y0;
        float wz = iz - (float)z0;
        const float* p = im + (z0 * HW_ + y0 * W_ + x0);
        f32x2 a = *(const f32x2*)(p);
        f32x2 c = *(const f32x2*)(p + W_);
        f32x2 e = *(const f32x2*)(p + HW_);
        f32x2 f = *(const f32x2*)(p + HW_ + W_);
        float c00 = a.x + (a.y - a.x) * wx;
        float c01 = c.x + (c.y - c.x) * wx;
        float c10 = e.x + (e.y - e.x) * wx;
        float c11 = f.x + (f.y - f.x) * wx;
        float c0 = c00 + (c01 - c00) * wy;
        float c1 = c10 + (c11 - c10) * wy;
        return c0 + (c1 - c0) * wz;
    };

    // one voxel: LDS window read (single final-offset clamp) + queue on miss
    auto process = [&](int z, int s, float gdx, float gdy, float gdz,
                       int uzTop) {
        float ix = fminf(fmaxf((float)x + gdx, 0.f), (float)(W_ - 1));
        float iy = fminf(fmaxf((float)y + gdy, 0.f), (float)(H_ - 1));
        float iz = fminf(fmaxf((float)z + gdz, 0.f), (float)(D_ - 1));

        int x0 = min((int)ix, W_ - 2);
        int y0 = min((int)iy, H_ - 2);
        int z0 = min((int)iz, D_ - 2);
        float wx = ix - (float)x0;
        float wy = iy - (float)y0;
        float wz = iz - (float)z0;

        int ux = x0 - rx, uy = y0 - ry, uz = z0 - vz0;
        bool in = ((unsigned)ux <= (unsigned)(RX_ - 2)) &
                  ((unsigned)uy <= (unsigned)(RY_ - 2)) &
                  ((unsigned)uz <= (unsigned)uzTop);

        int o0 = uz * SLICE_ + uy * RX_ + ux;   // raw; may be out of range
        o0 = min(max(o0, 0), LIM_);             // memory-safe (garbage on miss)
        int o1 = min(o0 + SLICE_, LIM_);

        float v000, v001, v010, v011, v100, v101, v110, v111;
        ldpair(o0,       v000, v001);
        ldpair(o0 + RX_, v010, v011);
        ldpair(o1,       v100, v101);
        ldpair(o1 + RX_, v110, v111);

        float c00 = v000 + (v001 - v000) * wx;
        float c01 = v010 + (v011 - v010) * wx;
        float c10 = v100 + (v101 - v100) * wx;
        float c11 = v110 + (v111 - v110) * wx;
        float c0 = c00 + (c01 - c00) * wy;
        float c1 = c10 + (c11 - c10) * wy;
        float res = c0 + (c1 - c0) * wz;

        bool do_store = in;
        if (!in) {
            int idx = atomicAdd(&qcount, 1);
            if (idx < QCAP_) {
                qdat[idx] = f32x4{__int_as_float(s), gdx, gdy, gdz};
            } else {
                res = gglobal(x, y, z, gdx, gdy, gdz);
                do_store = true;
            }
        }
        if (do_store) __builtin_nontemporal_store(res, op + s);
    };

    // ---- phase B issue: load slices [zlo+12, min(D,zlo+28)) into regs ----
    int zB0 = zlo + 12;
    int pcntB = (min(D_, zlo + 28) - zB0) * CPS_;
    f32x4 bv0, bv1, bv2, bv3, bv4;
    int   sl0, sl1, sl2, sl3, sl4;      // u32 index of chunk start (even)
    bool  bm0, bm1, bm2, bm3, bm4;
    {
#define ISSUE_B(J, BV, SL, BM)                                                 \
        {                                                                      \
            int c = tid + (J << 10);                                           \
            BM = c < pcntB;                                                    \
            int si  = c / CPS_;                                                \
            int rem = c - si * CPS_;                                           \
            int zs  = zB0 + si;                                                \
            SL = (zs - vz0) * (SLICE_ / 2) + rem * 2;                          \
            if (BM) {                                                          \
                int row = rem / CPR_;                                          \
                int col = rem - row * CPR_;                                    \
                BV = *(const f32x4*)(im + (zs * H_ + ry + row) * W_ + rx + col * 4); \
            }                                                                  \
        }
        ISSUE_B(0, bv0, sl0, bm0)
        ISSUE_B(1, bv1, sl1, bm1)
        ISSUE_B(2, bv2, sl2, bm2)
        ISSUE_B(3, bv3, sl3, bm3)
        ISSUE_B(4, bv4, sl4, bm4)
#undef ISSUE_B
    }

    // ---- compute k=0,1 against phase-A window (slots 0..15 -> uz<=14) ----
    process(zlo + zz,     s0,           ddxv[0], ddy[0], ddz[0], 14);
    process(zlo + zz + 4, s0 + 4 * HW_, ddxv[1], ddy[1], ddz[1], 14);

    // ---- commit phase-B regs to LDS slots 16..31 (disjoint from A reads) --
    if (bm0) { tile32[sl0] = bfpack(bv0.x, bv0.y); tile32[sl0 + 1] = bfpack(bv0.z, bv0.w); }
    if (bm1) { tile32[sl1] = bfpack(bv1.x, bv1.y); tile32[sl1 + 1] = bfpack(bv1.z, bv1.w); }
    if (bm2) { tile32[sl2] = bfpack(bv2.x, bv2.y); tile32[sl2 + 1] = bfpack(bv2.z, bv2.w); }
    if (bm3) { tile32[sl3] = bfpack(bv3.x, bv3.y); tile32[sl3 + 1] = bfpack(bv3.z, bv3.w); }
    if (bm4) { tile32[sl4] = bfpack(bv4.x, bv4.y); tile32[sl4 + 1] = bfpack(bv4.z, bv4.w); }
    __syncthreads();

    // ---- compute k=2..4 with the full window (uz<=30) ----
    process(zlo + zz + 8,  s0 + 8 * HW_,  ddxv[2], ddy[2], ddz[2], 30);
    process(zlo + zz + 12, s0 + 12 * HW_, ddxv[3], ddy[3], ddz[3], 30);
    process(zlo + zz + 16, s0 + 16 * HW_, ddxv[4], ddy[4], ddz[4], 30);

    __syncthreads();

    // ---- epilogue: resolve queued misses (ddf from queue, gathers L2-hot) --
    int n = min(qcount, QCAP_);
    for (int i = tid; i < n; i += 1024) {
        f32x4 q = qdat[i];
        int sq = __float_as_int(q.x);
        int zq = sq / HW_;
        int rq = sq - zq * HW_;
        int yq = rq / W_;
        int xq = rq - yq * W_;
        float res = gglobal(xq, yq, zq, q.y, q.z, q.w);
        op[sq] = res;
    }
}

extern "C" void kernel_launch(void* const* d_in, const int* in_sizes, int n_in,
                              void* d_out, int out_size, void* d_ws, size_t ws_size,
                              hipStream_t stream) {
    const float* img = (const float*)d_in[0];
    const float* ddf = (const float*)d_in[1];
    float*       out = (float*)d_out;

    warp3d_kernel<<<NBLK_, 1024, 0, stream>>>(img, ddf, out);
}

// Round 17
// 85.218 us; speedup vs baseline: 1.2541x; 1.0388x over previous
//
#include <hip/hip_runtime.h>

// 3D trilinear warp (grid_sample, align_corners=True, border padding).
// image: (B=2, 1, 160, 192, 192) f32 | ddf: (B,3,D,H,W) f32 (dz,dy,dx voxels)
//
// FINAL (= Round-11, measured best 85.3us): one-shot f32 LDS window,
// split-phase staging, miss queue + global epilogue.
//  - Grid 6(x) x 24(y) x 8(zh) x 2(b) = 2304 blocks = exactly 9/CU, 1024 thr.
//  - Window: 32 slices [zlo-4, zlo+28) of a 52x23 region, slot = z-(zlo-4)
//    (direct mapping). 153 KB LDS.
//  - Phase A: stage slices [zlo-4, zlo+12) -> barrier -> ISSUE upper-16-slice
//    loads into regs (T14) -> compute k=0,1 (window-top uz<=14) -> commit
//    regs to LDS slots 16..31 (disjoint from phase-A reads) -> barrier ->
//    compute k=2..4 with full window (uz<=30).
//  - Branchless LDS reads via single final-offset clamp (garbage aliased
//    reads only on miss, discarded). Misses push {s,dx,dy,dz} to LDS queue;
//    epilogue gathers from global (L2-hot), never re-reads ddf from HBM.
//  - XCD-chunked bijective swizzle (2304 % 8 == 0).
//
// Optimization history: 197 (naive) -> 193 (vec4) -> 166 (gather-batch+XCD
// swizzle) -> 120 (3D tiling) -> 101 (rolling-z LDS) -> 89 (miss-queue) ->
// 87.5 (one-shot window) -> 85.3 (split-phase). Rejected: 2-block co-res
// (95.5), compiler batching (90.5), XOR swizzle (wrong), bf16 LDS (88.5+).

typedef float f32x4 __attribute__((ext_vector_type(4)));
typedef float f32x2 __attribute__((ext_vector_type(2)));

constexpr int D_ = 160, H_ = 192, W_ = 192;
constexpr int HW_ = H_ * W_;
constexpr int N_  = D_ * HW_;

constexpr int TX_ = 32, TY_ = 8;
constexpr int XT_ = W_ / TX_;               // 6
constexpr int YT_ = H_ / TY_;               // 24
constexpr int ZH_ = 8;
constexpr int ZRUN_ = D_ / ZH_;             // 20
constexpr int NBLK_ = XT_ * YT_ * ZH_ * 2;  // 2304 = 9 * 256 exactly

constexpr int RX_ = 52, RY_ = 23, NZ_ = 32;
constexpr int SLICE_ = RX_ * RY_;           // 1196 floats
constexpr int CPS_ = SLICE_ / 4;            // 299 dwordx4 chunks per slice
constexpr int CPR_ = RX_ / 4;               // 13 chunks per row
constexpr int LIM_ = NZ_ * SLICE_ - RX_ - 2;// 38218: max safe base offset
constexpr int QCAP_ = 512;

__global__ __launch_bounds__(1024) void warp3d_kernel(
    const float* __restrict__ img,
    const float* __restrict__ ddf,
    float* __restrict__ out)
{
    __shared__ float tile[NZ_ * SLICE_];    // 153,088 B
    __shared__ f32x4 qdat[QCAP_];           // 8,192 B
    __shared__ int   qcount;

    constexpr int CPX = NBLK_ / 8;          // 288
    int bid = blockIdx.x;
    int swz = (bid & 7) * CPX + (bid >> 3);

    int tx = swz % XT_;  int t1 = swz / XT_;
    int ty = t1 % YT_;   int t2 = t1 / YT_;
    int zh = t2 % ZH_;   int b  = t2 / ZH_;

    int zlo = zh * ZRUN_;
    int vz0 = zlo - 4;                      // virtual window origin (may be <0)
    int rx = min(max(tx * TX_ - 8, 0), W_ - RX_);
    int ry = min(max(ty * TY_ - 7, 0), H_ - RY_);

    const float* im = img + (size_t)b * N_;
    const float* dp = ddf + (size_t)b * 3 * N_;
    float*       op = out + (size_t)b * N_;

    int tid = threadIdx.x;
    int xi = tid & 31;
    int yy = (tid >> 5) & 7;
    int zz = tid >> 8;                      // 0..3

    int x = tx * TX_ + xi;
    int y = ty * TY_ + yy;
    int s0 = ((zlo + zz) * H_ + y) * W_ + x;

    // ---- ddf loads for all 5 voxels (latency hides under phase-A staging) --
    float ddz[5], ddy[5], ddxv[5];
#pragma unroll
    for (int k = 0; k < 5; ++k) {
        int s = s0 + k * 4 * HW_;
        ddz[k]  = __builtin_nontemporal_load(dp + s);
        ddy[k]  = __builtin_nontemporal_load(dp + N_ + s);
        ddxv[k] = __builtin_nontemporal_load(dp + 2 * N_ + s);
    }

    if (tid == 0) qcount = 0;

    // ---- phase A: stage slices [max(0,vz0), zlo+12) -> slots [.,16) ----
    int pzA0 = max(0, vz0);
    int pcntA = (zlo + 12 - pzA0) * CPS_;
    for (int c = tid; c < pcntA; c += 1024) {
        int si  = c / CPS_;
        int rem = c - si * CPS_;
        int zs  = pzA0 + si;
        int row = rem / CPR_;
        int col = rem - row * CPR_;
        f32x4 v = *(const f32x4*)(im + (zs * H_ + ry + row) * W_ + rx + col * 4);
        *(f32x4*)&tile[(zs - vz0) * SLICE_ + rem * 4] = v;
    }
    __syncthreads();

    // global gather (overflow + epilogue path)
    auto gglobal = [&](int vx, int vy, int vz,
                       float gdx, float gdy, float gdz) -> float {
        float ix = fminf(fmaxf((float)vx + gdx, 0.f), (float)(W_ - 1));
        float iy = fminf(fmaxf((float)vy + gdy, 0.f), (float)(H_ - 1));
        float iz = fminf(fmaxf((float)vz + gdz, 0.f), (float)(D_ - 1));
        int x0 = min((int)ix, W_ - 2);
        int y0 = min((int)iy, H_ - 2);
        int z0 = min((int)iz, D_ - 2);
        float wx = ix - (float)x0;
        float wy = iy - (float)y0;
        float wz = iz - (float)z0;
        const float* p = im + (z0 * HW_ + y0 * W_ + x0);
        f32x2 a = *(const f32x2*)(p);
        f32x2 c = *(const f32x2*)(p + W_);
        f32x2 e = *(const f32x2*)(p + HW_);
        f32x2 f = *(const f32x2*)(p + HW_ + W_);
        float c00 = a.x + (a.y - a.x) * wx;
        float c01 = c.x + (c.y - c.x) * wx;
        float c10 = e.x + (e.y - e.x) * wx;
        float c11 = f.x + (f.y - f.x) * wx;
        float c0 = c00 + (c01 - c00) * wy;
        float c1 = c10 + (c11 - c10) * wy;
        return c0 + (c1 - c0) * wz;
    };

    // one voxel: LDS window read (single final-offset clamp) + queue on miss
    auto process = [&](int z, int s, float gdx, float gdy, float gdz,
                       int uzTop) {
        float ix = fminf(fmaxf((float)x + gdx, 0.f), (float)(W_ - 1));
        float iy = fminf(fmaxf((float)y + gdy, 0.f), (float)(H_ - 1));
        float iz = fminf(fmaxf((float)z + gdz, 0.f), (float)(D_ - 1));

        int x0 = min((int)ix, W_ - 2);
        int y0 = min((int)iy, H_ - 2);
        int z0 = min((int)iz, D_ - 2);
        float wx = ix - (float)x0;
        float wy = iy - (float)y0;
        float wz = iz - (float)z0;

        int ux = x0 - rx, uy = y0 - ry, uz = z0 - vz0;
        bool in = ((unsigned)ux <= (unsigned)(RX_ - 2)) &
                  ((unsigned)uy <= (unsigned)(RY_ - 2)) &
                  ((unsigned)uz <= (unsigned)uzTop);

        int o0 = uz * SLICE_ + uy * RX_ + ux;   // raw; may be out of range
        o0 = min(max(o0, 0), LIM_);             // memory-safe (garbage on miss)
        int o1 = min(o0 + SLICE_, LIM_);

        float v000 = tile[o0];       float v001 = tile[o0 + 1];
        float v010 = tile[o0 + RX_]; float v011 = tile[o0 + RX_ + 1];
        float v100 = tile[o1];       float v101 = tile[o1 + 1];
        float v110 = tile[o1 + RX_]; float v111 = tile[o1 + RX_ + 1];

        float c00 = v000 + (v001 - v000) * wx;
        float c01 = v010 + (v011 - v010) * wx;
        float c10 = v100 + (v101 - v100) * wx;
        float c11 = v110 + (v111 - v110) * wx;
        float c0 = c00 + (c01 - c00) * wy;
        float c1 = c10 + (c11 - c10) * wy;
        float res = c0 + (c1 - c0) * wz;

        bool do_store = in;
        if (!in) {
            int idx = atomicAdd(&qcount, 1);
            if (idx < QCAP_) {
                qdat[idx] = f32x4{__int_as_float(s), gdx, gdy, gdz};
            } else {
                res = gglobal(x, y, z, gdx, gdy, gdz);
                do_store = true;
            }
        }
        if (do_store) __builtin_nontemporal_store(res, op + s);
    };

    // ---- phase B issue: load slices [zlo+12, min(D,zlo+28)) into regs ----
    int zB0 = zlo + 12;
    int pcntB = (min(D_, zlo + 28) - zB0) * CPS_;
    f32x4 bv0, bv1, bv2, bv3, bv4;
    int   sl0, sl1, sl2, sl3, sl4;
    bool  bm0, bm1, bm2, bm3, bm4;
    {
#define ISSUE_B(J, BV, SL, BM)                                                 \
        {                                                                      \
            int c = tid + (J << 10);                                           \
            BM = c < pcntB;                                                    \
            int si  = c / CPS_;                                                \
            int rem = c - si * CPS_;                                           \
            int zs  = zB0 + si;                                                \
            SL = (zs - vz0) * SLICE_ + rem * 4;                                \
            if (BM) {                                                          \
                int row = rem / CPR_;                                          \
                int col = rem - row * CPR_;                                    \
                BV = *(const f32x4*)(im + (zs * H_ + ry + row) * W_ + rx + col * 4); \
            }                                                                  \
        }
        ISSUE_B(0, bv0, sl0, bm0)
        ISSUE_B(1, bv1, sl1, bm1)
        ISSUE_B(2, bv2, sl2, bm2)
        ISSUE_B(3, bv3, sl3, bm3)
        ISSUE_B(4, bv4, sl4, bm4)
#undef ISSUE_B
    }

    // ---- compute k=0,1 against phase-A window (slots 0..15 -> uz<=14) ----
    process(zlo + zz,     s0,           ddxv[0], ddy[0], ddz[0], 14);
    process(zlo + zz + 4, s0 + 4 * HW_, ddxv[1], ddy[1], ddz[1], 14);

    // ---- commit phase-B regs to LDS slots 16..31 (disjoint from A reads) --
    if (bm0) *(f32x4*)&tile[sl0] = bv0;
    if (bm1) *(f32x4*)&tile[sl1] = bv1;
    if (bm2) *(f32x4*)&tile[sl2] = bv2;
    if (bm3) *(f32x4*)&tile[sl3] = bv3;
    if (bm4) *(f32x4*)&tile[sl4] = bv4;
    __syncthreads();

    // ---- compute k=2..4 with the full window (uz<=30) ----
    process(zlo + zz + 8,  s0 + 8 * HW_,  ddxv[2], ddy[2], ddz[2], 30);
    process(zlo + zz + 12, s0 + 12 * HW_, ddxv[3], ddy[3], ddz[3], 30);
    process(zlo + zz + 16, s0 + 16 * HW_, ddxv[4], ddy[4], ddz[4], 30);

    __syncthreads();

    // ---- epilogue: resolve queued misses (ddf from queue, gathers L2-hot) --
    int n = min(qcount, QCAP_);
    for (int i = tid; i < n; i += 1024) {
        f32x4 q = qdat[i];
        int sq = __float_as_int(q.x);
        int zq = sq / HW_;
        int rq = sq - zq * HW_;
        int yq = rq / W_;
        int xq = rq - yq * W_;
        float res = gglobal(xq, yq, zq, q.y, q.z, q.w);
        op[sq] = res;
    }
}

extern "C" void kernel_launch(void* const* d_in, const int* in_sizes, int n_in,
                              void* d_out, int out_size, void* d_ws, size_t ws_size,
                              hipStream_t stream) {
    const float* img = (const float*)d_in[0];
    const float* ddf = (const float*)d_in[1];
    float*       out = (float*)d_out;

    warp3d_kernel<<<NBLK_, 1024, 0, stream>>>(img, ddf, out);
}

// Round 18
// 83.766 us; speedup vs baseline: 1.2758x; 1.0173x over previous
//
#include <hip/hip_runtime.h>

// 3D trilinear warp (grid_sample, align_corners=True, border padding).
// image: (B=2, 1, 160, 192, 192) f32 | ddf: (B,3,D,H,W) f32 (dz,dy,dx voxels)
//
// Round-18: R11 structure + async global_load_lds staging (both phases).
//  - Grid 6 x 24 x 8 x 2 = 2304 blocks = exactly 9/CU, 1024 threads.
//  - Window: 32 slices [zlo-4, zlo+28) of a 52x23 region (153 KB), direct
//    slot mapping. LDS dest pattern is linear in chunk id -> satisfies the
//    wave-uniform-base + lane*16 requirement of global_load_lds (guards are
//    prefix-active per wave; global source is per-lane arbitrary).
//  - Phase A: issue global_load_lds for slices [zlo-4, zlo+12) -> barrier
//    (drains vmcnt) -> Phase B: fire global_load_lds for slices [zlo+12,
//    zlo+28) into slots 16..31 (disjoint from k0/k1 reads) -> compute k=0,1
//    -> barrier (drains phase-B) -> compute k=2..4 with the full window.
//    No VGPR round-trip, no ds_writes, no explicit commit.
//  - Branchless LDS reads via single final-offset clamp; misses push
//    {s,dx,dy,dz} to an LDS queue; epilogue gathers from global (L2-hot).
//  - XCD-chunked bijective swizzle (2304 % 8 == 0).

typedef float f32x4 __attribute__((ext_vector_type(4)));
typedef float f32x2 __attribute__((ext_vector_type(2)));

constexpr int D_ = 160, H_ = 192, W_ = 192;
constexpr int HW_ = H_ * W_;
constexpr int N_  = D_ * HW_;

constexpr int TX_ = 32, TY_ = 8;
constexpr int XT_ = W_ / TX_;               // 6
constexpr int YT_ = H_ / TY_;               // 24
constexpr int ZH_ = 8;
constexpr int ZRUN_ = D_ / ZH_;             // 20
constexpr int NBLK_ = XT_ * YT_ * ZH_ * 2;  // 2304 = 9 * 256 exactly

constexpr int RX_ = 52, RY_ = 23, NZ_ = 32;
constexpr int SLICE_ = RX_ * RY_;           // 1196 floats (multiple of 4)
constexpr int CPS_ = SLICE_ / 4;            // 299 dwordx4 chunks per slice
constexpr int CPR_ = RX_ / 4;               // 13 chunks per row
constexpr int LIM_ = NZ_ * SLICE_ - RX_ - 2;// 38218: max safe base offset
constexpr int QCAP_ = 512;

__device__ __forceinline__ void gload_lds16(const float* src, float* dst) {
    __builtin_amdgcn_global_load_lds(
        (const __attribute__((address_space(1))) unsigned*)src,
        (__attribute__((address_space(3))) unsigned*)dst,
        16, 0, 0);
}

__global__ __launch_bounds__(1024) void warp3d_kernel(
    const float* __restrict__ img,
    const float* __restrict__ ddf,
    float* __restrict__ out)
{
    __shared__ float tile[NZ_ * SLICE_];    // 153,088 B
    __shared__ f32x4 qdat[QCAP_];           // 8,192 B
    __shared__ int   qcount;

    constexpr int CPX = NBLK_ / 8;          // 288
    int bid = blockIdx.x;
    int swz = (bid & 7) * CPX + (bid >> 3);

    int tx = swz % XT_;  int t1 = swz / XT_;
    int ty = t1 % YT_;   int t2 = t1 / YT_;
    int zh = t2 % ZH_;   int b  = t2 / ZH_;

    int zlo = zh * ZRUN_;
    int vz0 = zlo - 4;                      // virtual window origin (may be <0)
    int rx = min(max(tx * TX_ - 8, 0), W_ - RX_);   // always %4==0
    int ry = min(max(ty * TY_ - 7, 0), H_ - RY_);

    const float* im = img + (size_t)b * N_;
    const float* dp = ddf + (size_t)b * 3 * N_;
    float*       op = out + (size_t)b * N_;

    int tid = threadIdx.x;
    int xi = tid & 31;
    int yy = (tid >> 5) & 7;
    int zz = tid >> 8;                      // 0..3

    int x = tx * TX_ + xi;
    int y = ty * TY_ + yy;
    int s0 = ((zlo + zz) * H_ + y) * W_ + x;

    // ---- ddf loads for all 5 voxels (drain together with phase-A staging) --
    float ddz[5], ddy[5], ddxv[5];
#pragma unroll
    for (int k = 0; k < 5; ++k) {
        int s = s0 + k * 4 * HW_;
        ddz[k]  = __builtin_nontemporal_load(dp + s);
        ddy[k]  = __builtin_nontemporal_load(dp + N_ + s);
        ddxv[k] = __builtin_nontemporal_load(dp + 2 * N_ + s);
    }

    if (tid == 0) qcount = 0;

    // ---- phase A: async-stage slices [max(0,vz0), zlo+12) -> slots [.,16) --
    int pzA0 = max(0, vz0);
    int pcntA = (zlo + 12 - pzA0) * CPS_;
    int A0f   = (pzA0 - vz0) * SLICE_;
#pragma unroll
    for (int k = 0; k < 5; ++k) {
        int c = tid + (k << 10);
        if (c < pcntA) {                    // prefix-active within each wave
            int si  = c / CPS_;
            int rem = c - si * CPS_;
            int zs  = pzA0 + si;
            int row = rem / CPR_;
            int col = rem - row * CPR_;
            gload_lds16(im + (zs * H_ + ry + row) * W_ + rx + col * 4,
                        &tile[A0f + 4 * c]);
        }
    }
    __syncthreads();                        // drains vmcnt: window A ready

    // ---- phase B: fire-and-forget async-stage slices [zlo+12, zlo+28) ----
    // Dest slots 16..31 are disjoint from k0/k1's in-window reads (<=15);
    // concurrent garbage reads by miss voxels are discarded.
    {
        int zB0 = zlo + 12;
        int pcntB = (min(D_, zlo + 28) - zB0) * CPS_;
        int B0f = (zB0 - vz0) * SLICE_;     // 16 * SLICE_
#pragma unroll
        for (int k = 0; k < 5; ++k) {
            int c = tid + (k << 10);
            if (c < pcntB) {                // prefix-active within each wave
                int si  = c / CPS_;
                int rem = c - si * CPS_;
                int zs  = zB0 + si;
                int row = rem / CPR_;
                int col = rem - row * CPR_;
                gload_lds16(im + (zs * H_ + ry + row) * W_ + rx + col * 4,
                            &tile[B0f + 4 * c]);
            }
        }
    }

    // global gather (overflow + epilogue path)
    auto gglobal = [&](int vx, int vy, int vz,
                       float gdx, float gdy, float gdz) -> float {
        float ix = fminf(fmaxf((float)vx + gdx, 0.f), (float)(W_ - 1));
        float iy = fminf(fmaxf((float)vy + gdy, 0.f), (float)(H_ - 1));
        float iz = fminf(fmaxf((float)vz + gdz, 0.f), (float)(D_ - 1));
        int x0 = min((int)ix, W_ - 2);
        int y0 = min((int)iy, H_ - 2);
        int z0 = min((int)iz, D_ - 2);
        float wx = ix - (float)x0;
        float wy = iy - (float)y0;
        float wz = iz - (float)z0;
        const float* p = im + (z0 * HW_ + y0 * W_ + x0);
        f32x2 a = *(const f32x2*)(p);
        f32x2 c = *(const f32x2*)(p + W_);
        f32x2 e = *(const f32x2*)(p + HW_);
        f32x2 f = *(const f32x2*)(p + HW_ + W_);
        float c00 = a.x + (a.y - a.x) * wx;
        float c01 = c.x + (c.y - c.x) * wx;
        float c10 = e.x + (e.y - e.x) * wx;
        float c11 = f.x + (f.y - f.x) * wx;
        float c0 = c00 + (c01 - c00) * wy;
        float c1 = c10 + (c11 - c10) * wy;
        return c0 + (c1 - c0) * wz;
    };

    // one voxel: LDS window read (single final-offset clamp) + queue on miss
    auto process = [&](int z, int s, float gdx, float gdy, float gdz,
                       int uzTop) {
        float ix = fminf(fmaxf((float)x + gdx, 0.f), (float)(W_ - 1));
        float iy = fminf(fmaxf((float)y + gdy, 0.f), (float)(H_ - 1));
        float iz = fminf(fmaxf((float)z + gdz, 0.f), (float)(D_ - 1));

        int x0 = min((int)ix, W_ - 2);
        int y0 = min((int)iy, H_ - 2);
        int z0 = min((int)iz, D_ - 2);
        float wx = ix - (float)x0;
        float wy = iy - (float)y0;
        float wz = iz - (float)z0;

        int ux = x0 - rx, uy = y0 - ry, uz = z0 - vz0;
        bool in = ((unsigned)ux <= (unsigned)(RX_ - 2)) &
                  ((unsigned)uy <= (unsigned)(RY_ - 2)) &
                  ((unsigned)uz <= (unsigned)uzTop);

        int o0 = uz * SLICE_ + uy * RX_ + ux;   // raw; may be out of range
        o0 = min(max(o0, 0), LIM_);             // memory-safe (garbage on miss)
        int o1 = min(o0 + SLICE_, LIM_);

        float v000 = tile[o0];       float v001 = tile[o0 + 1];
        float v010 = tile[o0 + RX_]; float v011 = tile[o0 + RX_ + 1];
        float v100 = tile[o1];       float v101 = tile[o1 + 1];
        float v110 = tile[o1 + RX_]; float v111 = tile[o1 + RX_ + 1];

        float c00 = v000 + (v001 - v000) * wx;
        float c01 = v010 + (v011 - v010) * wx;
        float c10 = v100 + (v101 - v100) * wx;
        float c11 = v110 + (v111 - v110) * wx;
        float c0 = c00 + (c01 - c00) * wy;
        float c1 = c10 + (c11 - c10) * wy;
        float res = c0 + (c1 - c0) * wz;

        bool do_store = in;
        if (!in) {
            int idx = atomicAdd(&qcount, 1);
            if (idx < QCAP_) {
                qdat[idx] = f32x4{__int_as_float(s), gdx, gdy, gdz};
            } else {
                res = gglobal(x, y, z, gdx, gdy, gdz);
                do_store = true;
            }
        }
        if (do_store) __builtin_nontemporal_store(res, op + s);
    };

    // ---- compute k=0,1 against phase-A window (slots 0..15 -> uz<=14) ----
    process(zlo + zz,     s0,           ddxv[0], ddy[0], ddz[0], 14);
    process(zlo + zz + 4, s0 + 4 * HW_, ddxv[1], ddy[1], ddz[1], 14);

    __syncthreads();                        // drains phase-B loads: full window

    // ---- compute k=2..4 with the full window (uz<=30) ----
    process(zlo + zz + 8,  s0 + 8 * HW_,  ddxv[2], ddy[2], ddz[2], 30);
    process(zlo + zz + 12, s0 + 12 * HW_, ddxv[3], ddy[3], ddz[3], 30);
    process(zlo + zz + 16, s0 + 16 * HW_, ddxv[4], ddy[4], ddz[4], 30);

    __syncthreads();

    // ---- epilogue: resolve queued misses (ddf from queue, gathers L2-hot) --
    int n = min(qcount, QCAP_);
    for (int i = tid; i < n; i += 1024) {
        f32x4 q = qdat[i];
        int sq = __float_as_int(q.x);
        int zq = sq / HW_;
        int rq = sq - zq * HW_;
        int yq = rq / W_;
        int xq = rq - yq * W_;
        float res = gglobal(xq, yq, zq, q.y, q.z, q.w);
        op[sq] = res;
    }
}

extern "C" void kernel_launch(void* const* d_in, const int* in_sizes, int n_in,
                              void* d_out, int out_size, void* d_ws, size_t ws_size,
                              hipStream_t stream) {
    const float* img = (const float*)d_in[0];
    const float* ddf = (const float*)d_in[1];
    float*       out = (float*)d_out;

    warp3d_kernel<<<NBLK_, 1024, 0, stream>>>(img, ddf, out);
}